// Round 15
// baseline (92.029 us; speedup 1.0000x reference)
//
#include <hip/hip_runtime.h>
#include <math.h>

#define NXC 432
#define NYC 496
#define CELLS (NYC * NXC)          // 214272
#define BATCH 4
#define PTOT 48000
#define EPSC 1e-3f
#define TCELLS 128                 // tile (CELLS % 128 == 0 -> no batch straddle)

typedef float f2v    __attribute__((ext_vector_type(2)));
typedef float f4v    __attribute__((ext_vector_type(4)));
typedef float f32x16 __attribute__((ext_vector_type(16)));
typedef __bf16 bf16x8 __attribute__((ext_vector_type(8)));
typedef unsigned int u32x2 __attribute__((ext_vector_type(2)));
typedef unsigned int u32x4 __attribute__((ext_vector_type(4)));

// Fold table (SoA, coalesced; 4 KB): see r10 layout.
__device__ __forceinline__ unsigned int pk_bf16(float a, float b) {
    __bf16 ha = (__bf16)a, hb = (__bf16)b;
    unsigned short ua = __builtin_bit_cast(unsigned short, ha);
    unsigned short ub = __builtin_bit_cast(unsigned short, hb);
    return ((unsigned int)ub << 16) | ua;
}

__global__ __launch_bounds__(64) void fold_kernel(
    const float* __restrict__ w1, const float* __restrict__ bn1,
    const float* __restrict__ w2, const float* __restrict__ bn2,
    const float* __restrict__ wf1, const float* __restrict__ wf2,
    unsigned int* __restrict__ tbl)
{
    const int c = threadIdx.x;
    const float s1 = bn1[c] * rsqrtf(bn1[192 + c] + EPSC);
    const float w10 = w1[c],       w11 = w1[64 + c],  w12 = w1[128 + c];
    const float w13 = w1[192 + c], w14 = w1[256 + c], w15 = w1[320 + c];
    const float w16 = w1[384 + c], w17 = w1[448 + c], w18 = w1[512 + c];
    const float w19 = w1[576 + c];
    const float AX = (w10 + w14 + w17) * s1;
    const float AY = (w11 + w15 + w18) * s1;
    const float AZ = (w12 + w16 + w19) * s1;
    const float AI = w13 * s1;

    const float s2 = bn2[c] * rsqrtf(bn2[192 + c] + EPSC);
    float B[8];
#pragma unroll
    for (int k = 0; k < 8; ++k) B[k] = w2[k * 64 + c] * s2;

    ((u32x2*)tbl)[c]         = (u32x2){pk_bf16(AX, AY), pk_bf16(AZ, AI)};
    ((u32x4*)(tbl + 128))[c] = (u32x4){pk_bf16(B[0], B[1]), pk_bf16(B[2], B[3]),
                                       pk_bf16(B[4], B[5]), pk_bf16(B[6], B[7])};
    ((f4v*)(tbl + 384))[c]   = (f4v){bn1[64 + c] - bn1[128 + c] * s1,
                                     w14 * s1, w15 * s1, w16 * s1};
    ((f4v*)(tbl + 640))[c]   = (f4v){w17 * s1, w18 * s1, w19 * s1,
                                     bn2[64 + c] - bn2[128 + c] * s2};
    ((f2v*)(tbl + 896))[c]   = (f2v){wf1[c], wf2[c]};
}

// Tiny scatter: build cell -> pillar map from coords only.
__global__ __launch_bounds__(256) void scatter_kernel(
    const int* __restrict__ coords, int* __restrict__ map)
{
    const int t = blockIdx.x * 256 + threadIdx.x;
    if (t < PTOT) {
        const int4 c = *(const int4*)(coords + t * 4);
        map[c.x * CELLS + (c.y + c.z * NXC + c.w)] = t;
    }
}

__device__ __forceinline__ float rmax16(const f32x16 d) {
    const float t0 = fmaxf(fmaxf(d[0], d[1]), d[2]);
    const float t1 = fmaxf(fmaxf(d[3], d[4]), d[5]);
    const float t2 = fmaxf(fmaxf(d[6], d[7]), d[8]);
    const float t3 = fmaxf(fmaxf(d[9], d[10]), d[11]);
    const float t4 = fmaxf(fmaxf(d[12], d[13]), d[14]);
    const float u0 = fmaxf(fmaxf(t0, t1), t2);
    const float u1 = fmaxf(fmaxf(t3, t4), d[15]);
    return fmaxf(u0, u1);
}

// ---------------------------------------------------------------------------
// FUSED kernel: per 128-cell tile, each wave ballots its 32 cells, computes
// the dual-PFN inline for each occupied cell (wave-uniform loop; MFMA uses
// all 64 lanes), writes into transpose-LDS, then dense-emits. comb buffer
// eliminated; pfe compute overlaps the write drain.
// Layouts (learn_hip m74/m101): D col=lane&31, row=(reg&3)+8*(reg>>2)+4*(lane>>5);
// A row=lane&31, k=(lane>>5)*8+e; B col=lane&31, k=(lane>>5)*8+e.
// ---------------------------------------------------------------------------
__global__ __launch_bounds__(256) void fused_kernel(
    const float* __restrict__ pillars, const unsigned int* __restrict__ tbl,
    const float* __restrict__ fbn1, const float* __restrict__ fbn2,
    const int* __restrict__ coords, const int* __restrict__ num_points,
    const int* __restrict__ map, float* __restrict__ out)
{
    __shared__ float lds[64 * 132];
    __shared__ int mcell[128];
    const int tid  = threadIdx.x;
    const int lane = tid & 63;
    const int ln   = lane & 31;
    const bool hi  = lane >= 32;
    const int w    = tid >> 6;
    const int gbase = blockIdx.x * TCELLS;
    const int cellbase = w * 32;

    // wave's 32 cells (hi lanes duplicate lo lanes)
    const int m = map[gbase + cellbase + ln];
    if (!hi) mcell[cellbase + ln] = m;
    unsigned int mask = (unsigned int)(__ballot(m >= 0) & 0xffffffffu);

    if (mask) {
        // hoisted per-channel constants (SoA, coalesced; L2-hot 4 KB)
        const u32x2* At = (const u32x2*)tbl;
        const u32x4* Bt = (const u32x4*)(tbl + 128);
        const f4v*   Ct = (const f4v*)(tbl + 384);
        const f4v*   Dt = (const f4v*)(tbl + 640);
        const f2v*   Et = (const f2v*)(tbl + 896);

        bf16x8 bfr1[2], bfr2[2];
        f4v k0c[2], k1c[2];
        f2v wfc[2];
#pragma unroll
        for (int j = 0; j < 2; ++j) {
            const int c = ln + j * 32;
            const u32x2 a2 = At[c];
            const u32x4 w1v = {a2.x, a2.y, 0u, 0u};
            bfr1[j] = __builtin_bit_cast(bf16x8, w1v);
            bfr2[j] = __builtin_bit_cast(bf16x8, Bt[c]);
            k0c[j] = Ct[c];
            k1c[j] = Dt[c];
            wfc[j] = Et[c];
        }
        const float r1s = fbn1[0] * rsqrtf(fbn1[3] + EPSC);
        const float r1b = fbn1[1], r1m = fbn1[2];
        const float r2s = fbn2[0] * rsqrtf(fbn2[3] + EPSC);
        const float r2b = fbn2[1], r2m = fbn2[2];

        while (mask) {
            const int i = __builtin_ctz(mask);
            mask &= mask - 1;
            const int p = __builtin_amdgcn_readfirstlane(__shfl(m, i));

            const float* pl = pillars + (size_t)p * 256;
            const f4v v0 = *(const f4v*)(pl + ln * 8);
            const f4v v1 = *(const f4v*)(pl + ln * 8 + 4);
            const int cc1 = coords[p * 4 + 1];
            const int cc2 = coords[p * 4 + 2];
            const int cc3 = coords[p * 4 + 3];
            const float invn = 1.0f / (float)num_points[p];

            // mean xyz over all 32 points (reference does NOT mask)
            float sx = v0.x, sy = v0.y, sz = v0.z;
#pragma unroll
            for (int off = 1; off <= 16; off <<= 1) {
                sx += __shfl_xor(sx, off);
                sy += __shfl_xor(sy, off);
                sz += __shfl_xor(sz, off);
            }
            const float mxm = sx * invn, mym = sy * invn, mzm = sz * invn;
            const float cx = cc3 * 0.16f + 0.08f;
            const float cy = cc2 * 0.16f + (-39.6f);
            const float cz = cc1 * 4.0f  + (-1.0f);

            float C0c[2];
#pragma unroll
            for (int j = 0; j < 2; ++j)
                C0c[j] = k0c[j].x - (mxm * k0c[j].y + mym * k0c[j].z + mzm * k0c[j].w)
                       - (cx * k1c[j].x + cy * k1c[j].y + cz * k1c[j].z);

            // A fragment: lo lanes bf16-hi (k=0..7), hi lanes bf16-lo residual
            bf16x8 a;
            {
                const float f[8] = {v0.x, v0.y, v0.z, v0.w, v1.x, v1.y, v1.z, v1.w};
#pragma unroll
                for (int e = 0; e < 8; ++e) {
                    const __bf16 h8 = (__bf16)f[e];
                    const __bf16 l8 = (__bf16)(f[e] - (float)h8);
                    a[e] = hi ? l8 : h8;
                }
            }

            const f32x16 zero = {};
            const f32x16 d0 = __builtin_amdgcn_mfma_f32_32x32x16_bf16(a, bfr1[0], zero, 0, 0, 0);
            const f32x16 d1 = __builtin_amdgcn_mfma_f32_32x32x16_bf16(a, bfr1[1], zero, 0, 0, 0);
            const f32x16 d2 = __builtin_amdgcn_mfma_f32_32x32x16_bf16(a, bfr2[0], zero, 0, 0, 0);
            const f32x16 d3 = __builtin_amdgcn_mfma_f32_32x32x16_bf16(a, bfr2[1], zero, 0, 0, 0);

            float m0 = rmax16(d0), m1 = rmax16(d1), m2 = rmax16(d2), m3 = rmax16(d3);
            m0 = fmaxf(m0, __shfl_xor(m0, 32));
            m1 = fmaxf(m1, __shfl_xor(m1, 32));
            m2 = fmaxf(m2, __shfl_xor(m2, 32));
            m3 = fmaxf(m3, __shfl_xor(m3, 32));

            const float f1A = fmaxf(m0 + C0c[0], 0.f);
            const float f1B = fmaxf(m1 + C0c[1], 0.f);
            const float f2A = fmaxf(m2 + k1c[0].w, 0.f);
            const float f2B = fmaxf(m3 + k1c[1].w, 0.f);

            float dd1 = f1A * wfc[0].x + f1B * wfc[1].x;
            float dd2 = f2A * wfc[0].y + f2B * wfc[1].y;
#pragma unroll
            for (int off = 1; off <= 16; off <<= 1) {
                dd1 += __shfl_xor(dd1, off);
                dd2 += __shfl_xor(dd2, off);
            }
            const float sc1 = (dd1 - r1m) * r1s + r1b;
            const float sc2 = (dd2 - r2m) * r2s + r2b;
            const float a0 = 1.0f / (1.0f + expf(sc2 - sc1));

            if (!hi) {
                const int cp = cellbase + i;
                lds[ln * 132 + cp]        = fmaf(f1A - f2A, a0, f2A);
                lds[(ln + 32) * 132 + cp] = fmaf(f1B - f2B, a0, f2B);
            }
        }
    }
    __syncthreads();

    // dense emit: coalesced float4 plain stores (91% peak BW, r11)
    const int b = gbase / CELLS;
    const int L = gbase - b * CELLS;
    float* obase = out + (size_t)(b * 64) * CELLS + L;
#pragma unroll
    for (int r = 0; r < 8; r++) {
        const int idx = r * 256 + tid;
        const int f = idx >> 5;
        const int g = idx & 31;
        const int4 mg = *(const int4*)&mcell[g * 4];
        f4v v = {0.f, 0.f, 0.f, 0.f};
        if ((mg.x & mg.y & mg.z & mg.w) >= 0) {   // at least one occupied
            const f4v ww = *(const f4v*)(lds + f * 132 + g * 4);
            v.x = (mg.x < 0) ? 0.f : ww.x;
            v.y = (mg.y < 0) ? 0.f : ww.y;
            v.z = (mg.z < 0) ? 0.f : ww.z;
            v.w = (mg.w < 0) ? 0.f : ww.w;
        }
        *(f4v*)(obase + (size_t)f * CELLS + g * 4) = v;
    }
}

extern "C" void kernel_launch(void* const* d_in, const int* in_sizes, int n_in,
                              void* d_out, int out_size, void* d_ws, size_t ws_size,
                              hipStream_t stream) {
    const float* pillars = (const float*)d_in[0];
    const float* w1      = (const float*)d_in[1];
    const float* bn1     = (const float*)d_in[2];
    const float* w2      = (const float*)d_in[3];
    const float* bn2     = (const float*)d_in[4];
    const float* wf1     = (const float*)d_in[5];
    const float* wf2     = (const float*)d_in[6];
    const float* fbn1    = (const float*)d_in[7];
    const float* fbn2    = (const float*)d_in[8];
    const int*   coords  = (const int*)d_in[9];
    const int*   nump    = (const int*)d_in[10];
    float* out = (float*)d_out;

    int*   map  = (int*)d_ws;
    unsigned int* tbl = (unsigned int*)((char*)d_ws + (size_t)BATCH * CELLS * 4);

    (void)hipMemsetAsync(map, 0xFF, (size_t)BATCH * CELLS * 4, stream);  // all -1
    fold_kernel<<<1, 64, 0, stream>>>(w1, bn1, w2, bn2, wf1, wf2, tbl);
    scatter_kernel<<<(PTOT + 255) / 256, 256, 0, stream>>>(coords, map);
    fused_kernel<<<(BATCH * CELLS) / TCELLS, 256, 0, stream>>>(
        pillars, tbl, fbn1, fbn2, coords, nump, map, out);
}

// Round 16
// 78.656 us; speedup vs baseline: 1.1700x; 1.1700x over previous
//
#include <hip/hip_runtime.h>
#include <math.h>

#define NXC 432
#define NYC 496
#define CELLS (NYC * NXC)          // 214272
#define BATCH 4
#define PTOT 48000
#define EPSC 1e-3f
#define TCELLS 128                 // emit tile (CELLS % 128 == 0)

typedef float f2v    __attribute__((ext_vector_type(2)));
typedef float f4v    __attribute__((ext_vector_type(4)));
typedef float f32x16 __attribute__((ext_vector_type(16)));
typedef __bf16 bf16x8 __attribute__((ext_vector_type(8)));
typedef unsigned int u32x2 __attribute__((ext_vector_type(2)));
typedef unsigned int u32x4 __attribute__((ext_vector_type(4)));

// Fold table (SoA, coalesced per-lane reads; 4 KB): see r10 layout comment.
__device__ __forceinline__ unsigned int pk_bf16(float a, float b) {
    __bf16 ha = (__bf16)a, hb = (__bf16)b;
    unsigned short ua = __builtin_bit_cast(unsigned short, ha);
    unsigned short ub = __builtin_bit_cast(unsigned short, hb);
    return ((unsigned int)ub << 16) | ua;
}

__global__ __launch_bounds__(64) void fold_kernel(
    const float* __restrict__ w1, const float* __restrict__ bn1,
    const float* __restrict__ w2, const float* __restrict__ bn2,
    const float* __restrict__ wf1, const float* __restrict__ wf2,
    unsigned int* __restrict__ tbl)
{
    const int c = threadIdx.x;
    const float s1 = bn1[c] * rsqrtf(bn1[192 + c] + EPSC);
    const float w10 = w1[c],       w11 = w1[64 + c],  w12 = w1[128 + c];
    const float w13 = w1[192 + c], w14 = w1[256 + c], w15 = w1[320 + c];
    const float w16 = w1[384 + c], w17 = w1[448 + c], w18 = w1[512 + c];
    const float w19 = w1[576 + c];
    const float AX = (w10 + w14 + w17) * s1;
    const float AY = (w11 + w15 + w18) * s1;
    const float AZ = (w12 + w16 + w19) * s1;
    const float AI = w13 * s1;

    const float s2 = bn2[c] * rsqrtf(bn2[192 + c] + EPSC);
    float B[8];
#pragma unroll
    for (int k = 0; k < 8; ++k) B[k] = w2[k * 64 + c] * s2;

    ((u32x2*)tbl)[c]         = (u32x2){pk_bf16(AX, AY), pk_bf16(AZ, AI)};
    ((u32x4*)(tbl + 128))[c] = (u32x4){pk_bf16(B[0], B[1]), pk_bf16(B[2], B[3]),
                                       pk_bf16(B[4], B[5]), pk_bf16(B[6], B[7])};
    ((f4v*)(tbl + 384))[c]   = (f4v){bn1[64 + c] - bn1[128 + c] * s1,
                                     w14 * s1, w15 * s1, w16 * s1};
    ((f4v*)(tbl + 640))[c]   = (f4v){w17 * s1, w18 * s1, w19 * s1,
                                     bn2[64 + c] - bn2[128 + c] * s2};
    ((f2v*)(tbl + 896))[c]   = (f2v){wf1[c], wf2[c]};
}

// max of 16 regs via v_max3-friendly triples
__device__ __forceinline__ float rmax16(const f32x16 d) {
    const float t0 = fmaxf(fmaxf(d[0], d[1]), d[2]);
    const float t1 = fmaxf(fmaxf(d[3], d[4]), d[5]);
    const float t2 = fmaxf(fmaxf(d[6], d[7]), d[8]);
    const float t3 = fmaxf(fmaxf(d[9], d[10]), d[11]);
    const float t4 = fmaxf(fmaxf(d[12], d[13]), d[14]);
    const float u0 = fmaxf(fmaxf(t0, t1), t2);
    const float u1 = fmaxf(fmaxf(t3, t4), d[15]);
    return fmaxf(u0, u1);
}

// ---------------------------------------------------------------------------
// Kernel 1: dual-PFN via MFMA; 4 pillars per wave (r12 structure — best
// measured cold: ~41us; fusion (r15) and 1-pillar (r14) both regressed).
// Layouts (learn_hip m74/m101): D col=lane&31, row=(reg&3)+8*(reg>>2)+4*(lane>>5);
// A row=lane&31, k=(lane>>5)*8+e; B col=lane&31, k=(lane>>5)*8+e.
// ---------------------------------------------------------------------------
__global__ __launch_bounds__(256) void pfe_kernel(
    const float* __restrict__ pillars, const unsigned int* __restrict__ tbl,
    const float* __restrict__ fbn1, const float* __restrict__ fbn2,
    const int* __restrict__ coords, const int* __restrict__ num_points,
    float* __restrict__ comb, int* __restrict__ map)
{
    const int tid  = threadIdx.x;
    const int lane = tid & 63;
    const int ln   = lane & 31;
    const bool hi  = lane >= 32;
    const int q = __builtin_amdgcn_readfirstlane(blockIdx.x * 4 + (tid >> 6));
    const int pbase = q * 4;

    // hoisted per-channel constants (pillar-invariant, SoA, coalesced)
    const u32x2* At = (const u32x2*)tbl;
    const u32x4* Bt = (const u32x4*)(tbl + 128);
    const f4v*   Ct = (const f4v*)(tbl + 384);
    const f4v*   Dt = (const f4v*)(tbl + 640);
    const f2v*   Et = (const f2v*)(tbl + 896);

    bf16x8 bfr1[2], bfr2[2];
    f4v k0c[2], k1c[2];
    f2v wfc[2];
#pragma unroll
    for (int j = 0; j < 2; ++j) {
        const int c = ln + j * 32;
        const u32x2 a2 = At[c];
        const u32x4 w1v = {a2.x, a2.y, 0u, 0u};
        bfr1[j] = __builtin_bit_cast(bf16x8, w1v);
        bfr2[j] = __builtin_bit_cast(bf16x8, Bt[c]);
        k0c[j] = Ct[c];
        k1c[j] = Dt[c];
        wfc[j] = Et[c];
    }
    const float r1s = fbn1[0] * rsqrtf(fbn1[3] + EPSC);
    const float r1b = fbn1[1], r1m = fbn1[2];
    const float r2s = fbn2[0] * rsqrtf(fbn2[3] + EPSC);
    const float r2b = fbn2[1], r2m = fbn2[2];

    // issue all 4 pillars' loads up-front (8 outstanding VMEM ops)
    f4v pv0[4], pv1[4];
    int cb[4], cc1[4], cc2[4], cc3[4];
    float invn[4];
#pragma unroll
    for (int i = 0; i < 4; ++i) {
        const float* pl = pillars + (size_t)(pbase + i) * 256;
        pv0[i] = *(const f4v*)(pl + ln * 8);
        pv1[i] = *(const f4v*)(pl + ln * 8 + 4);
        cb[i]  = coords[(pbase + i) * 4 + 0];
        cc1[i] = coords[(pbase + i) * 4 + 1];
        cc2[i] = coords[(pbase + i) * 4 + 2];
        cc3[i] = coords[(pbase + i) * 4 + 3];
        invn[i] = 1.0f / (float)num_points[pbase + i];
    }

#pragma unroll
    for (int i = 0; i < 4; ++i) {
        const f4v v0 = pv0[i], v1 = pv1[i];

        // mean xyz over all 32 points (reference does NOT mask)
        float sx = v0.x, sy = v0.y, sz = v0.z;
#pragma unroll
        for (int off = 1; off <= 16; off <<= 1) {
            sx += __shfl_xor(sx, off);
            sy += __shfl_xor(sy, off);
            sz += __shfl_xor(sz, off);
        }
        const float mxm = sx * invn[i], mym = sy * invn[i], mzm = sz * invn[i];
        const float cx = cc3[i] * 0.16f + 0.08f;
        const float cy = cc2[i] * 0.16f + (-39.6f);
        const float cz = cc1[i] * 4.0f  + (-1.0f);

        float C0c[2];
#pragma unroll
        for (int j = 0; j < 2; ++j)
            C0c[j] = k0c[j].x - (mxm * k0c[j].y + mym * k0c[j].z + mzm * k0c[j].w)
                   - (cx * k1c[j].x + cy * k1c[j].y + cz * k1c[j].z);

        // A fragment: lo lanes bf16-hi (k=0..7), hi lanes bf16-lo residual
        bf16x8 a;
        {
            const float f[8] = {v0.x, v0.y, v0.z, v0.w, v1.x, v1.y, v1.z, v1.w};
#pragma unroll
            for (int e = 0; e < 8; ++e) {
                const __bf16 h8 = (__bf16)f[e];
                const __bf16 l8 = (__bf16)(f[e] - (float)h8);
                a[e] = hi ? l8 : h8;
            }
        }

        const f32x16 zero = {};
        const f32x16 d0 = __builtin_amdgcn_mfma_f32_32x32x16_bf16(a, bfr1[0], zero, 0, 0, 0);
        const f32x16 d1 = __builtin_amdgcn_mfma_f32_32x32x16_bf16(a, bfr1[1], zero, 0, 0, 0);
        const f32x16 d2 = __builtin_amdgcn_mfma_f32_32x32x16_bf16(a, bfr2[0], zero, 0, 0, 0);
        const f32x16 d3 = __builtin_amdgcn_mfma_f32_32x32x16_bf16(a, bfr2[1], zero, 0, 0, 0);

        float m0 = rmax16(d0), m1 = rmax16(d1), m2 = rmax16(d2), m3 = rmax16(d3);
        m0 = fmaxf(m0, __shfl_xor(m0, 32));
        m1 = fmaxf(m1, __shfl_xor(m1, 32));
        m2 = fmaxf(m2, __shfl_xor(m2, 32));
        m3 = fmaxf(m3, __shfl_xor(m3, 32));

        const float f1A = fmaxf(m0 + C0c[0], 0.f);
        const float f1B = fmaxf(m1 + C0c[1], 0.f);
        const float f2A = fmaxf(m2 + k1c[0].w, 0.f);
        const float f2B = fmaxf(m3 + k1c[1].w, 0.f);

        // attention scalars (each 32-half holds the full 64-channel set)
        float dd1 = f1A * wfc[0].x + f1B * wfc[1].x;
        float dd2 = f2A * wfc[0].y + f2B * wfc[1].y;
#pragma unroll
        for (int off = 1; off <= 16; off <<= 1) {
            dd1 += __shfl_xor(dd1, off);
            dd2 += __shfl_xor(dd2, off);
        }
        const float sc1 = (dd1 - r1m) * r1s + r1b;
        const float sc2 = (dd2 - r2m) * r2s + r2b;
        const float a0 = 1.0f / (1.0f + expf(sc2 - sc1));

        const int p = pbase + i;
        if (!hi) {
            comb[p * 64 + ln]      = fmaf(f1A - f2A, a0, f2A);
            comb[p * 64 + 32 + ln] = fmaf(f1B - f2B, a0, f2B);
        }
        if (lane == 0) {
            const int lin = cc1[i] + cc2[i] * NXC + cc3[i];
            map[cb[i] * CELLS + lin] = p;
        }
    }
}

// ---------------------------------------------------------------------------
// Kernel 2: dense emit; plain stores (NT cost ~10us — r11 A/B; plain hits
// 7.3 TB/s = 91% peak). Occupied cells gather into LDS; empty 4-cell groups
// store zero-float4 directly.
// ---------------------------------------------------------------------------
__global__ __launch_bounds__(256) void emit_kernel(
    const int* __restrict__ map, const float* __restrict__ comb,
    float* __restrict__ out)
{
    __shared__ float lds[64 * 132];
    __shared__ int mcell[128];
    const int t = threadIdx.x;
    const int gbase = blockIdx.x * TCELLS;

    {
        const int c = t >> 1;
        const int h = (t & 1) * 32;
        const int m = map[gbase + c];
        if ((t & 1) == 0) mcell[c] = m;
        if (m >= 0) {
            const float* src = comb + (size_t)m * 64 + h;
            float* dst = lds + h * 132 + c;
#pragma unroll
            for (int j = 0; j < 8; j++) {
                const float4 v = *(const float4*)(src + j * 4);
                dst[(j * 4 + 0) * 132] = v.x;
                dst[(j * 4 + 1) * 132] = v.y;
                dst[(j * 4 + 2) * 132] = v.z;
                dst[(j * 4 + 3) * 132] = v.w;
            }
        }
    }
    __syncthreads();

    const int b = gbase / CELLS;
    const int L = gbase - b * CELLS;
    float* obase = out + (size_t)(b * 64) * CELLS + L;
#pragma unroll
    for (int r = 0; r < 8; r++) {
        const int idx = r * 256 + t;
        const int f = idx >> 5;
        const int g = idx & 31;
        const int4 mg = *(const int4*)&mcell[g * 4];
        f4v v = {0.f, 0.f, 0.f, 0.f};
        if ((mg.x & mg.y & mg.z & mg.w) >= 0) {
            const f4v w = *(const f4v*)(lds + f * 132 + g * 4);
            v.x = (mg.x < 0) ? 0.f : w.x;
            v.y = (mg.y < 0) ? 0.f : w.y;
            v.z = (mg.z < 0) ? 0.f : w.z;
            v.w = (mg.w < 0) ? 0.f : w.w;
        }
        *(f4v*)(obase + (size_t)f * CELLS + g * 4) = v;
    }
}

extern "C" void kernel_launch(void* const* d_in, const int* in_sizes, int n_in,
                              void* d_out, int out_size, void* d_ws, size_t ws_size,
                              hipStream_t stream) {
    const float* pillars = (const float*)d_in[0];
    const float* w1      = (const float*)d_in[1];
    const float* bn1     = (const float*)d_in[2];
    const float* w2      = (const float*)d_in[3];
    const float* bn2     = (const float*)d_in[4];
    const float* wf1     = (const float*)d_in[5];
    const float* wf2     = (const float*)d_in[6];
    const float* fbn1    = (const float*)d_in[7];
    const float* fbn2    = (const float*)d_in[8];
    const int*   coords  = (const int*)d_in[9];
    const int*   nump    = (const int*)d_in[10];
    float* out = (float*)d_out;

    int*   map  = (int*)d_ws;
    float* comb = (float*)((char*)d_ws + (size_t)BATCH * CELLS * 4);
    unsigned int* tbl = (unsigned int*)((char*)d_ws + (size_t)BATCH * CELLS * 4
                                        + (size_t)PTOT * 64 * 4);

    (void)hipMemsetAsync(map, 0xFF, (size_t)BATCH * CELLS * 4, stream);  // all -1
    fold_kernel<<<1, 64, 0, stream>>>(w1, bn1, w2, bn2, wf1, wf2, tbl);
    pfe_kernel<<<PTOT / 16, 256, 0, stream>>>(pillars, tbl, fbn1, fbn2,
                                              coords, nump, comb, map);
    emit_kernel<<<(BATCH * CELLS) / TCELLS, 256, 0, stream>>>(map, comb, out);
}